// Round 2
// baseline (33.551 us; speedup 1.0000x reference)
//
#include <hip/hip_runtime.h>
#include <hip/hip_cooperative_groups.h>

namespace cg = cooperative_groups;

#define CL_BATCH   256
#define CL_FEAT    512
#define CL_BLOCKS  64
#define CL_THREADS 256                      // 4 waves/block
#define CL_ROWS_PER_BLOCK (CL_BATCH / CL_BLOCKS)  // 4
#define CL_CLAMP_MIN 1e-12f
#define CL_CLAMP_MAX 1e12f

// Single cooperative dispatch:
//  - each wave (64 lanes) computes one row's squared distance (2x float4/lane)
//  - block combines its 4 row-dists (fixed order) -> partials[blockIdx]
//  - grid.sync()
//  - block 0 / wave 0 reduces the 64 partials -> out[0]
// All reductions are fixed-order trees => bitwise deterministic.
__global__ __launch_bounds__(CL_THREADS) void center_loss_fused(
    const float* __restrict__ x,
    const int*   __restrict__ label,
    const float* __restrict__ centers,
    float*       __restrict__ partials,   // d_ws, CL_BLOCKS floats
    float*       __restrict__ out)
{
    const int wid  = threadIdx.x >> 6;    // 0..3
    const int lane = threadIdx.x & 63;    // 0..63
    const int b    = blockIdx.x * CL_ROWS_PER_BLOCK + wid;

    __shared__ float lds[CL_ROWS_PER_BLOCK];

    const int lbl = label[b];
    const float4* __restrict__ xr =
        reinterpret_cast<const float4*>(x + (size_t)b * CL_FEAT);
    const float4* __restrict__ cr =
        reinterpret_cast<const float4*>(centers + (size_t)lbl * CL_FEAT);

    // 512 floats/row = 128 float4 = 64 lanes x 2
    float4 xv0 = xr[lane];
    float4 cv0 = cr[lane];
    float4 xv1 = xr[lane + 64];
    float4 cv1 = cr[lane + 64];

    float s = 0.0f, d;
    d = xv0.x - cv0.x; s = fmaf(d, d, s);
    d = xv0.y - cv0.y; s = fmaf(d, d, s);
    d = xv0.z - cv0.z; s = fmaf(d, d, s);
    d = xv0.w - cv0.w; s = fmaf(d, d, s);
    d = xv1.x - cv1.x; s = fmaf(d, d, s);
    d = xv1.y - cv1.y; s = fmaf(d, d, s);
    d = xv1.z - cv1.z; s = fmaf(d, d, s);
    d = xv1.w - cv1.w; s = fmaf(d, d, s);

    // 64-lane butterfly reduce (fixed tree)
    #pragma unroll
    for (int off = 32; off > 0; off >>= 1)
        s += __shfl_down(s, off, 64);

    if (lane == 0) {
        s = fminf(fmaxf(s, CL_CLAMP_MIN), CL_CLAMP_MAX);  // per-row clamp
        lds[wid] = s;
    }
    __syncthreads();

    if (threadIdx.x == 0) {
        float p = (lds[0] + lds[1]) + (lds[2] + lds[3]);
        // agent-scope release store: visible across XCDs after grid sync
        __hip_atomic_store(&partials[blockIdx.x], p,
                           __ATOMIC_RELEASE, __HIP_MEMORY_SCOPE_AGENT);
    }

    cg::this_grid().sync();

    if (blockIdx.x == 0 && wid == 0) {
        // 64 partials, one per lane; agent-scope acquire load (bypass stale L1/L2)
        float v = __hip_atomic_load(&partials[lane],
                                    __ATOMIC_ACQUIRE, __HIP_MEMORY_SCOPE_AGENT);
        #pragma unroll
        for (int off = 32; off > 0; off >>= 1)
            v += __shfl_down(v, off, 64);
        if (lane == 0)
            out[0] = v * (1.0f / (float)CL_BATCH);
    }
}

extern "C" void kernel_launch(void* const* d_in, const int* in_sizes, int n_in,
                              void* d_out, int out_size, void* d_ws, size_t ws_size,
                              hipStream_t stream)
{
    const float* x       = (const float*)d_in[0];   // [256, 512] f32
    const int*   label   = (const int*)d_in[1];     // [256] int
    const float* centers = (const float*)d_in[2];   // [100000, 512] f32
    float* out      = (float*)d_out;                // scalar f32
    float* partials = (float*)d_ws;                 // 64 floats scratch

    void* args[] = { (void*)&x, (void*)&label, (void*)&centers,
                     (void*)&partials, (void*)&out };
    hipLaunchCooperativeKernel((const void*)center_loss_fused,
                               dim3(CL_BLOCKS), dim3(CL_THREADS),
                               args, 0, stream);
}

// Round 3
// 13.647 us; speedup vs baseline: 2.4585x; 2.4585x over previous
//
#include <hip/hip_runtime.h>

#define CL_BATCH   256
#define CL_FEAT    512
#define CL_BLOCKS  64
#define CL_THREADS 256                            // 4 waves/block, 1 row/wave
#define CL_CLAMP_MIN 1e-12f
#define CL_CLAMP_MAX 1e12f

// ws layout: [0] uint32 arrival counter (memset to 0 each call)
//            [64..127] float partials[64] (offset 256 B)
#define CL_PARTIALS_OFF 256

// Single fused kernel, last-arriver final reduce.
//  - wave w of block b computes row (b*4 + w): 2x float4/lane squared-diff,
//    64-lane butterfly reduce, clamp -> lds[w]
//  - thread 0: block partial = fixed-order sum of lds[0..3], release-store
//    partials[b], then device-scope fetch_add on counter
//  - the block observing old==63 (all partials published) has wave 0
//    acquire-load partials[0..63] and reduce in a fixed tree -> out[0]
// Result is bitwise deterministic: the reduce order is fixed regardless of
// which block arrives last. No spinning, no co-residency assumption.
__global__ __launch_bounds__(CL_THREADS) void center_loss_fused(
    const float* __restrict__ x,
    const int*   __restrict__ label,
    const float* __restrict__ centers,
    unsigned int* __restrict__ counter,   // ws + 0, pre-zeroed via memset node
    float*       __restrict__ partials,   // ws + 256 B
    float*       __restrict__ out)
{
    const int wid  = threadIdx.x >> 6;    // 0..3
    const int lane = threadIdx.x & 63;    // 0..63
    const int b    = blockIdx.x * 4 + wid;

    __shared__ float lds[4];
    __shared__ int   is_last;

    const int lbl = label[b];
    const float4* __restrict__ xr =
        reinterpret_cast<const float4*>(x + (size_t)b * CL_FEAT);
    const float4* __restrict__ cr =
        reinterpret_cast<const float4*>(centers + (size_t)lbl * CL_FEAT);

    // 512 floats/row = 128 float4 = 64 lanes x 2
    float4 xv0 = xr[lane];
    float4 cv0 = cr[lane];
    float4 xv1 = xr[lane + 64];
    float4 cv1 = cr[lane + 64];

    float s = 0.0f, d;
    d = xv0.x - cv0.x; s = fmaf(d, d, s);
    d = xv0.y - cv0.y; s = fmaf(d, d, s);
    d = xv0.z - cv0.z; s = fmaf(d, d, s);
    d = xv0.w - cv0.w; s = fmaf(d, d, s);
    d = xv1.x - cv1.x; s = fmaf(d, d, s);
    d = xv1.y - cv1.y; s = fmaf(d, d, s);
    d = xv1.z - cv1.z; s = fmaf(d, d, s);
    d = xv1.w - cv1.w; s = fmaf(d, d, s);

    #pragma unroll
    for (int off = 32; off > 0; off >>= 1)
        s += __shfl_down(s, off, 64);

    if (lane == 0) {
        s = fminf(fmaxf(s, CL_CLAMP_MIN), CL_CLAMP_MAX);  // per-row clamp
        lds[wid] = s;
    }
    __syncthreads();

    if (threadIdx.x == 0) {
        float p = (lds[0] + lds[1]) + (lds[2] + lds[3]);
        __hip_atomic_store(&partials[blockIdx.x], p,
                           __ATOMIC_RELEASE, __HIP_MEMORY_SCOPE_AGENT);
        unsigned int old = __hip_atomic_fetch_add(counter, 1u,
                           __ATOMIC_ACQ_REL, __HIP_MEMORY_SCOPE_AGENT);
        is_last = (old == CL_BLOCKS - 1) ? 1 : 0;
    }
    __syncthreads();

    if (is_last && wid == 0) {
        float v = __hip_atomic_load(&partials[lane],
                                    __ATOMIC_ACQUIRE, __HIP_MEMORY_SCOPE_AGENT);
        #pragma unroll
        for (int off = 32; off > 0; off >>= 1)
            v += __shfl_down(v, off, 64);
        if (lane == 0)
            out[0] = v * (1.0f / (float)CL_BATCH);
    }
}

extern "C" void kernel_launch(void* const* d_in, const int* in_sizes, int n_in,
                              void* d_out, int out_size, void* d_ws, size_t ws_size,
                              hipStream_t stream)
{
    const float* x       = (const float*)d_in[0];   // [256, 512] f32
    const int*   label   = (const int*)d_in[1];     // [256] int
    const float* centers = (const float*)d_in[2];   // [100000, 512] f32
    float* out = (float*)d_out;                     // scalar f32

    unsigned int* counter = (unsigned int*)d_ws;
    float* partials = (float*)((char*)d_ws + CL_PARTIALS_OFF);

    // cheap 4-byte memset node: zero the arrival counter each call
    hipMemsetAsync(counter, 0, sizeof(unsigned int), stream);

    center_loss_fused<<<CL_BLOCKS, CL_THREADS, 0, stream>>>(
        x, label, centers, counter, partials, out);
}

// Round 4
// 11.269 us; speedup vs baseline: 2.9772x; 1.2110x over previous
//
#include <hip/hip_runtime.h>

#define CL_BATCH   256
#define CL_FEAT    512
#define CL_BLOCKS  64                 // 4 waves/block, 1 row per wave
#define CL_THREADS 256
#define CL_CLAMP_MIN 1e-12f
#define CL_CLAMP_MAX 1e12f

// Kernel 1: 64 blocks x 256 threads (4 waves). Wave w of block b computes
// row b*4+w: each lane 2x float4 from x-row and gathered center-row,
// squared-diff FMA chain, 64-lane butterfly reduce, clamp. Block combines
// its 4 row distances in fixed order -> partials[b]. Deterministic.
__global__ __launch_bounds__(CL_THREADS) void center_loss_rows(
    const float* __restrict__ x,
    const int*   __restrict__ label,
    const float* __restrict__ centers,
    float*       __restrict__ partials)   // d_ws, 64 floats
{
    const int wid  = threadIdx.x >> 6;    // 0..3
    const int lane = threadIdx.x & 63;    // 0..63
    const int b    = blockIdx.x * 4 + wid;

    __shared__ float lds[4];

    const int lbl = label[b];
    const float4* __restrict__ xr =
        reinterpret_cast<const float4*>(x + (size_t)b * CL_FEAT);
    const float4* __restrict__ cr =
        reinterpret_cast<const float4*>(centers + (size_t)lbl * CL_FEAT);

    // 512 floats/row = 128 float4 = 64 lanes x 2
    float4 xv0 = xr[lane];
    float4 cv0 = cr[lane];
    float4 xv1 = xr[lane + 64];
    float4 cv1 = cr[lane + 64];

    float s = 0.0f, d;
    d = xv0.x - cv0.x; s = fmaf(d, d, s);
    d = xv0.y - cv0.y; s = fmaf(d, d, s);
    d = xv0.z - cv0.z; s = fmaf(d, d, s);
    d = xv0.w - cv0.w; s = fmaf(d, d, s);
    d = xv1.x - cv1.x; s = fmaf(d, d, s);
    d = xv1.y - cv1.y; s = fmaf(d, d, s);
    d = xv1.z - cv1.z; s = fmaf(d, d, s);
    d = xv1.w - cv1.w; s = fmaf(d, d, s);

    #pragma unroll
    for (int off = 32; off > 0; off >>= 1)
        s += __shfl_down(s, off, 64);

    if (lane == 0) {
        s = fminf(fmaxf(s, CL_CLAMP_MIN), CL_CLAMP_MAX);  // per-row clamp
        lds[wid] = s;
    }
    __syncthreads();

    if (threadIdx.x == 0)
        partials[blockIdx.x] = (lds[0] + lds[1]) + (lds[2] + lds[3]);
}

// Kernel 2: one wave, one float per lane, fixed-tree reduce -> mean.
__global__ __launch_bounds__(64) void center_loss_reduce(
    const float* __restrict__ partials,
    float* __restrict__ out)
{
    const int t = threadIdx.x;        // 0..63
    float s = partials[t];

    #pragma unroll
    for (int off = 32; off > 0; off >>= 1)
        s += __shfl_down(s, off, 64);

    if (t == 0)
        out[0] = s * (1.0f / (float)CL_BATCH);
}

extern "C" void kernel_launch(void* const* d_in, const int* in_sizes, int n_in,
                              void* d_out, int out_size, void* d_ws, size_t ws_size,
                              hipStream_t stream)
{
    const float* x       = (const float*)d_in[0];   // [256, 512] f32
    const int*   label   = (const int*)d_in[1];     // [256] int
    const float* centers = (const float*)d_in[2];   // [100000, 512] f32
    float* out      = (float*)d_out;                // scalar f32
    float* partials = (float*)d_ws;                 // 64 floats scratch

    center_loss_rows<<<CL_BLOCKS, CL_THREADS, 0, stream>>>(x, label, centers, partials);
    center_loss_reduce<<<1, 64, 0, stream>>>(partials, out);
}